// Round 1
// baseline (771.174 us; speedup 1.0000x reference)
//
#include <hip/hip_runtime.h>
#include <hip/hip_bf16.h>

typedef __attribute__((ext_vector_type(8))) short short8;
typedef __attribute__((ext_vector_type(4))) float f32x4;
typedef __attribute__((ext_vector_type(4))) int i32x4;
typedef __attribute__((ext_vector_type(4))) unsigned u32x4;

#define NTOK 512
#define NEXP 16
#define TOPK 4
#define HD   2880
#define ID   2880
#define N1   5760   // 2*I
#define NGRP 90     // 32-value groups per row (H/32 == I/32)

// ---------------- async global->LDS (16B per lane) ----------------
__device__ __forceinline__ void async16(void* lds, const void* g) {
  __builtin_amdgcn_global_load_lds((const __attribute__((address_space(1))) unsigned*)g,
                                   (__attribute__((address_space(3))) unsigned*)lds,
                                   16, 0, 0);
}

// ---------------- MXFP4 nibble -> bf16 bits, scale folded in ----------------
// value = fp4(n) * 2^(sc-127). bf16 bits: exponent = (sc-1) + e  (e>=1),
// 0.5 case (e=0,m=1) -> exponent sc-1 exactly. K = (sc-1)<<7.
__device__ __forceinline__ unsigned dq_nib(int n, int K) {
  int e = (n >> 1) & 3;
  int m = n & 1;
  unsigned mag;
  if (e) mag = (unsigned)((K + (e << 7)) | (m << 6));
  else   mag = m ? (unsigned)K : 0u;
  return mag | ((unsigned)(n & 8) << 12);   // sign -> bit 15
}
__device__ __forceinline__ unsigned dq_byte(int b, int K) {
  return dq_nib(b & 15, K) | (dq_nib((b >> 4) & 15, K) << 16);
}

// ---------------- RMSNorm ----------------
__global__ __launch_bounds__(256)
void rmsnorm_k(const float* __restrict__ x, const float* __restrict__ nsc,
               float* __restrict__ tf, __hip_bfloat16* __restrict__ tb)
{
  int t = blockIdx.x;
  const float* xr = x + (size_t)t * HD;
  float s = 0.f;
  for (int i = threadIdx.x; i < HD; i += 256) { float v = xr[i]; s += v * v; }
#pragma unroll
  for (int o = 32; o > 0; o >>= 1) s += __shfl_down(s, o);
  __shared__ float red[4];
  if ((threadIdx.x & 63) == 0) red[threadIdx.x >> 6] = s;
  __syncthreads();
  float tot = red[0] + red[1] + red[2] + red[3];
  float rinv = rsqrtf(tot / (float)HD + 1e-5f);
  for (int i = threadIdx.x; i < HD; i += 256) {
    float v = xr[i] * rinv * nsc[i];
    tf[(size_t)t * HD + i] = v;
    tb[(size_t)t * HD + i] = __float2bfloat16(v);
  }
}

// ---------------- Router: logits -> top4 -> softmax -> expert lists ----------------
__global__ __launch_bounds__(256)
void router_k(const float* __restrict__ tf, const float* __restrict__ gw,
              const float* __restrict__ gb, float* __restrict__ wpair,
              int* __restrict__ cnt, int* __restrict__ tok_list, int* __restrict__ pair_list)
{
  int t = blockIdx.x;
  int tid = threadIdx.x;
  int e = tid >> 4, l16 = tid & 15;
  const float* tr = tf + (size_t)t * HD;
  float s = 0.f;
  for (int i = l16; i < HD; i += 16) s += tr[i] * gw[e * HD + i];
#pragma unroll
  for (int o = 1; o < 16; o <<= 1) s += __shfl_xor(s, o);
  __shared__ float logits[NEXP];
  if (l16 == 0) logits[e] = s + gb[e];
  __syncthreads();
  if (tid == 0) {
    float v[NEXP];
#pragma unroll
    for (int i = 0; i < NEXP; ++i) v[i] = logits[i];
    int idx[TOPK]; float val[TOPK];
#pragma unroll
    for (int k = 0; k < TOPK; ++k) {
      int bi = 0; float bv = -1e30f;
      for (int i = 0; i < NEXP; ++i) if (v[i] > bv) { bv = v[i]; bi = i; }
      idx[k] = bi; val[k] = bv; v[bi] = -1e30f;
    }
    float mx = val[0], sum = 0.f, w[TOPK];
#pragma unroll
    for (int k = 0; k < TOPK; ++k) { w[k] = __expf(val[k] - mx); sum += w[k]; }
#pragma unroll
    for (int k = 0; k < TOPK; ++k) {
      float wk = w[k] / sum;
      int ee = idx[k];
      int slot = atomicAdd(&cnt[ee], 1);
      tok_list[ee * NTOK + slot]  = t;
      pair_list[ee * NTOK + slot] = t * TOPK + k;
      wpair[t * TOPK + k] = wk;
    }
  }
}

// ---------------- Grouped GEMM (stage 1: t@W1^T + swiglu -> h; stage 2: h@W2^T -> o) ----------------
// Tile 128(M=tokens/slots) x 128(N=weight rows), BK=64. 4 waves, each 64x64.
// A: gathered bf16 rows via global_load_lds (pre-swizzled source).
// B: mxfp4 (int32-per-byte) dequanted in-register -> swizzled LDS.
template<int STAGE>
__global__ __launch_bounds__(256)
void moe_gemm(const __hip_bfloat16* __restrict__ Asrc,
              const int* __restrict__ Bblk, const int* __restrict__ Bscl,
              const float* __restrict__ Bbias,
              const int* __restrict__ cnt,
              const int* __restrict__ tok_list, const int* __restrict__ pair_list,
              __hip_bfloat16* __restrict__ h_out, float* __restrict__ o_out)
{
  constexpr int NDIM = (STAGE == 1) ? N1 : HD;
  const int e  = blockIdx.z;
  const int ne = cnt[e];
  const int m0 = blockIdx.y * 128;
  if (m0 >= ne) return;
  const int n0 = blockIdx.x * 128;
  const int tid = threadIdx.x;
  const int wave = tid >> 6, lane = tid & 63;

  __shared__ __align__(16) char Abuf[16384];  // [128 rows][128 B] bf16, XOR-swizzled
  __shared__ __align__(16) char Bbuf[16384];

  const int* glist = (STAGE == 1 ? tok_list : pair_list) + e * NTOK;
  const int* plist = pair_list + e * NTOK;

  // --- A staging bases (4 issues of 256 lanes x 16B) ---
  const char* agbase[4];
  char* aldsbase[4];
#pragma unroll
  for (int i = 0; i < 4; ++i) {
    int o   = i * 4096 + tid * 16;
    int row = o >> 7;
    int scb = (o & 127) ^ ((row & 7) << 4);   // inverse-swizzled source chunk
    int slot = m0 + row; if (slot > ne - 1) slot = ne - 1;
    int gidx = glist[slot];
    agbase[i]  = (const char*)Asrc + (size_t)gidx * (HD * 2) + scb;
    aldsbase[i] = Abuf + i * 4096 + wave * 1024;  // wave-uniform base, HW adds lane*16
  }

  // --- B staging constants: thread -> (row, group-half) ---
  const int brow = tid >> 1, bgrp = tid & 1;
  const int nidx = n0 + brow;
  const bool bvalid = (nidx < NDIM);
  const size_t brbase = (size_t)(e * NDIM + (bvalid ? nidx : 0)) * NGRP;
  char* bdst[4];
#pragma unroll
  for (int c = 0; c < 4; ++c) {
    int chunk = (bgrp * 4 + c) ^ (brow & 7);
    bdst[c] = Bbuf + brow * 128 + chunk * 16;
  }

  // --- MFMA fragment LDS offsets (k-independent) ---
  const int l15 = lane & 15, l4 = lane >> 4;
  const int wm = (wave >> 1) * 64, wn = (wave & 1) * 64;
  int aoff[4][2], boff[4][2];
#pragma unroll
  for (int f = 0; f < 4; ++f) {
    int ra = wm + f * 16 + l15;
    int rb = wn + f * 16 + l15;
#pragma unroll
    for (int kk = 0; kk < 2; ++kk) {
      aoff[f][kk] = ra * 128 + ((kk * 64 + l4 * 16) ^ ((ra & 7) << 4));
      boff[f][kk] = rb * 128 + ((kk * 64 + l4 * 16) ^ ((rb & 7) << 4));
    }
  }

  f32x4 zero = {0.f, 0.f, 0.f, 0.f};
  f32x4 acc[4][4];
#pragma unroll
  for (int a = 0; a < 4; ++a)
#pragma unroll
    for (int b = 0; b < 4; ++b) acc[a][b] = zero;

  for (int k0 = 0; k0 < HD; k0 += 64) {
    // A: async gather into LDS
#pragma unroll
    for (int i = 0; i < 4; ++i) async16(aldsbase[i], agbase[i] + k0 * 2);
    // B: load 16 int32 bytes (one 32-value group), dequant, swizzled ds_write
    if (bvalid) {
      const int g0 = (k0 >> 5) + bgrp;
      const i32x4* bp = (const i32x4*)(Bblk + (brbase + g0) * 16);
      i32x4 q0 = bp[0], q1 = bp[1], q2 = bp[2], q3 = bp[3];
      int sc = Bscl[brbase + g0];
      int K = (sc - 1) << 7;
      u32x4 w;
      w.x = dq_byte(q0.x, K); w.y = dq_byte(q0.y, K); w.z = dq_byte(q0.z, K); w.w = dq_byte(q0.w, K);
      *(u32x4*)bdst[0] = w;
      w.x = dq_byte(q1.x, K); w.y = dq_byte(q1.y, K); w.z = dq_byte(q1.z, K); w.w = dq_byte(q1.w, K);
      *(u32x4*)bdst[1] = w;
      w.x = dq_byte(q2.x, K); w.y = dq_byte(q2.y, K); w.z = dq_byte(q2.z, K); w.w = dq_byte(q2.w, K);
      *(u32x4*)bdst[2] = w;
      w.x = dq_byte(q3.x, K); w.y = dq_byte(q3.y, K); w.z = dq_byte(q3.z, K); w.w = dq_byte(q3.w, K);
      *(u32x4*)bdst[3] = w;
    }
    __syncthreads();
#pragma unroll
    for (int kk = 0; kk < 2; ++kk) {
      short8 af[4], bf[4];
#pragma unroll
      for (int f = 0; f < 4; ++f) {
        af[f] = *(const short8*)(Abuf + aoff[f][kk]);
        bf[f] = *(const short8*)(Bbuf + boff[f][kk]);
      }
#pragma unroll
      for (int ma = 0; ma < 4; ++ma)
#pragma unroll
        for (int nb = 0; nb < 4; ++nb)
          acc[ma][nb] = __builtin_amdgcn_mfma_f32_16x16x32_bf16(af[ma], bf[nb], acc[ma][nb], 0, 0, 0);
    }
    __syncthreads();
  }

  // --- epilogue ---
  if (STAGE == 1) {
#pragma unroll
    for (int ma = 0; ma < 4; ++ma) {
#pragma unroll
      for (int nb = 0; nb < 4; ++nb) {
        int ncol = n0 + wn + nb * 16 + l15;
        float bias = Bbias[e * NDIM + ncol];
#pragma unroll
        for (int j = 0; j < 4; ++j) {
          float u  = acc[ma][nb][j] + bias;
          float up = __shfl_xor(u, 1);
          int slot = m0 + wm + ma * 16 + l4 * 4 + j;
          if (!(lane & 1) && slot < ne) {
            float g  = fminf(u, 7.f);
            float lv = fminf(fmaxf(up, -7.f), 7.f);
            float hv = g / (1.f + __expf(-1.702f * g)) * (lv + 1.f);
            h_out[(size_t)plist[slot] * ID + (ncol >> 1)] = __float2bfloat16(hv);
          }
        }
      }
    }
  } else {
#pragma unroll
    for (int ma = 0; ma < 4; ++ma) {
#pragma unroll
      for (int nb = 0; nb < 4; ++nb) {
        int ncol = n0 + wn + nb * 16 + l15;
        if (ncol < NDIM) {
          float bias = Bbias[e * NDIM + ncol];
#pragma unroll
          for (int j = 0; j < 4; ++j) {
            int slot = m0 + wm + ma * 16 + l4 * 4 + j;
            if (slot < ne)
              o_out[(size_t)plist[slot] * HD + ncol] = acc[ma][nb][j] + bias;
          }
        }
      }
    }
  }
}

// ---------------- Final: out = x + sum_k w[t,k] * o[t,k,:] ----------------
__global__ __launch_bounds__(256)
void final_k(const float* __restrict__ x, const float* __restrict__ obuf,
             const float* __restrict__ wpair, float* __restrict__ out)
{
  int t = blockIdx.x;
  float w0 = wpair[t * 4 + 0], w1 = wpair[t * 4 + 1];
  float w2 = wpair[t * 4 + 2], w3 = wpair[t * 4 + 3];
  const float* o0 = obuf + (size_t)(t * 4) * HD;
  for (int i = threadIdx.x; i < HD; i += 256) {
    float r = x[(size_t)t * HD + i]
            + w0 * o0[i] + w1 * o0[HD + i] + w2 * o0[2 * HD + i] + w3 * o0[3 * HD + i];
    out[(size_t)t * HD + i] = r;
  }
}

extern "C" void kernel_launch(void* const* d_in, const int* in_sizes, int n_in,
                              void* d_out, int out_size, void* d_ws, size_t ws_size,
                              hipStream_t stream)
{
  const float* x    = (const float*)d_in[0];
  const float* nsc  = (const float*)d_in[1];
  const float* gw   = (const float*)d_in[2];
  const float* gb   = (const float*)d_in[3];
  const int*   b1   = (const int*)d_in[4];
  const int*   s1   = (const int*)d_in[5];
  const float* bia1 = (const float*)d_in[6];
  const int*   b2   = (const int*)d_in[7];
  const int*   s2   = (const int*)d_in[8];
  const float* bia2 = (const float*)d_in[9];
  float* out = (float*)d_out;

  char* ws = (char*)d_ws;
  size_t off = 0;
  auto alloc = [&](size_t bytes) {
    char* p = ws + off;
    off = (off + bytes + 255) & ~(size_t)255;
    return p;
  };
  float*           tf    = (float*)alloc((size_t)NTOK * HD * 4);
  __hip_bfloat16*  tb    = (__hip_bfloat16*)alloc((size_t)NTOK * HD * 2);
  __hip_bfloat16*  hbuf  = (__hip_bfloat16*)alloc((size_t)NTOK * TOPK * ID * 2);
  float*           obuf  = (float*)alloc((size_t)NTOK * TOPK * HD * 4);
  float*           wpair = (float*)alloc(NTOK * TOPK * 4);
  int*             cnt   = (int*)alloc(64);
  int*             tokl  = (int*)alloc(NEXP * NTOK * 4);
  int*             pairl = (int*)alloc(NEXP * NTOK * 4);

  hipMemsetAsync(cnt, 0, NEXP * sizeof(int), stream);
  rmsnorm_k<<<NTOK, 256, 0, stream>>>(x, nsc, tf, tb);
  router_k<<<NTOK, 256, 0, stream>>>(tf, gw, gb, wpair, cnt, tokl, pairl);
  moe_gemm<1><<<dim3(N1 / 128, 4, NEXP), 256, 0, stream>>>(tb, b1, s1, bia1, cnt, tokl, pairl, hbuf, nullptr);
  moe_gemm<2><<<dim3((HD + 127) / 128, 4, NEXP), 256, 0, stream>>>(hbuf, b2, s2, bia2, cnt, tokl, pairl, nullptr, obuf);
  final_k<<<NTOK, 256, 0, stream>>>(x, obuf, wpair, out);
}

// Round 3
// 560.904 us; speedup vs baseline: 1.3749x; 1.3749x over previous
//
#include <hip/hip_runtime.h>
#include <hip/hip_bf16.h>

typedef __attribute__((ext_vector_type(8))) short short8;
typedef __attribute__((ext_vector_type(4))) float f32x4;
typedef __attribute__((ext_vector_type(4))) int i32x4;
typedef __attribute__((ext_vector_type(4))) unsigned u32x4;

#define NTOK 512
#define NEXP 16
#define TOPK 4
#define HD   2880
#define ID   2880
#define N1   5760   // 2*I
#define NGRP 90     // 32-value groups per row
#define NKT  45     // HD/64 K-steps

// ---------------- async global->LDS (16B per lane) ----------------
__device__ __forceinline__ void async16(void* lds, const void* g) {
  __builtin_amdgcn_global_load_lds((const __attribute__((address_space(1))) unsigned*)g,
                                   (__attribute__((address_space(3))) unsigned*)lds,
                                   16, 0, 0);
}

__device__ __forceinline__ unsigned perm(unsigned hi, unsigned lo, unsigned sel) {
  return __builtin_amdgcn_perm(hi, lo, sel);
}

// ---------------- perm-LUT MXFP4 dequant (bit-exact bf16, scale folded) ----------------
__device__ __forceinline__ u32x4 dq_word4(unsigned p, unsigned hbl, unsigned hbh,
                                          unsigned lbl, unsigned lbh) {
  unsigned ph = p >> 4;
  unsigned il = p  & 0x07070707u, sl = p  & 0x08080808u;
  unsigned ih = ph & 0x07070707u, sh = ph & 0x08080808u;
  unsigned hbL = perm(hbh, hbl, il) | (sl << 4);
  unsigned lbL = perm(lbh, lbl, il);
  unsigned hbH = perm(hbh, hbl, ih) | (sh << 4);
  unsigned lbH = perm(lbh, lbl, ih);
  unsigned mL01 = perm(hbL, lbL, 0x05010400u);
  unsigned mL23 = perm(hbL, lbL, 0x07030602u);
  unsigned mH01 = perm(hbH, lbH, 0x05010400u);
  unsigned mH23 = perm(hbH, lbH, 0x07030602u);
  u32x4 w;
  w.x = perm(mH01, mL01, 0x05040100u);
  w.y = perm(mH01, mL01, 0x07060302u);
  w.z = perm(mH23, mL23, 0x05040100u);
  w.w = perm(mH23, mL23, 0x07060302u);
  return w;
}

__device__ __forceinline__ void dq_store(i32x4 q0, i32x4 q1, i32x4 q2, i32x4 q3, int sc,
                                         char* d0, char* d1, char* d2, char* d3) {
  unsigned m7 = (unsigned)((127 - sc) << 7);          // sc in [118,127]
  unsigned mm = m7 | (m7 << 16);
  unsigned e10 = (0x3F00u - m7) << 16;                // entry0 stays exact 0
  unsigned e32 = 0x3FC03F80u - mm;
  unsigned e54 = 0x40404000u - mm;
  unsigned e76 = 0x40C04080u - mm;
  unsigned hbl = perm(e32, e10, 0x07050301u);         // hi bytes, entries 0-3
  unsigned hbh = perm(e76, e54, 0x07050301u);         // hi bytes, entries 4-7
  unsigned lbl = perm(e32, e10, 0x06040200u);         // lo bytes, entries 0-3
  unsigned lbh = perm(e76, e54, 0x06040200u);
  unsigned pk;
  pk = (unsigned)q0.x | ((unsigned)q0.y << 8) | ((unsigned)q0.z << 16) | ((unsigned)q0.w << 24);
  *(u32x4*)d0 = dq_word4(pk, hbl, hbh, lbl, lbh);
  pk = (unsigned)q1.x | ((unsigned)q1.y << 8) | ((unsigned)q1.z << 16) | ((unsigned)q1.w << 24);
  *(u32x4*)d1 = dq_word4(pk, hbl, hbh, lbl, lbh);
  pk = (unsigned)q2.x | ((unsigned)q2.y << 8) | ((unsigned)q2.z << 16) | ((unsigned)q2.w << 24);
  *(u32x4*)d2 = dq_word4(pk, hbl, hbh, lbl, lbh);
  pk = (unsigned)q3.x | ((unsigned)q3.y << 8) | ((unsigned)q3.z << 16) | ((unsigned)q3.w << 24);
  *(u32x4*)d3 = dq_word4(pk, hbl, hbh, lbl, lbh);
}

// ---------------- RMSNorm ----------------
__global__ __launch_bounds__(256)
void rmsnorm_k(const float* __restrict__ x, const float* __restrict__ nsc,
               float* __restrict__ tf, __hip_bfloat16* __restrict__ tb)
{
  int t = blockIdx.x;
  const float* xr = x + (size_t)t * HD;
  float s = 0.f;
  for (int i = threadIdx.x; i < HD; i += 256) { float v = xr[i]; s += v * v; }
#pragma unroll
  for (int o = 32; o > 0; o >>= 1) s += __shfl_down(s, o);
  __shared__ float red[4];
  if ((threadIdx.x & 63) == 0) red[threadIdx.x >> 6] = s;
  __syncthreads();
  float tot = red[0] + red[1] + red[2] + red[3];
  float rinv = rsqrtf(tot / (float)HD + 1e-5f);
  for (int i = threadIdx.x; i < HD; i += 256) {
    float v = xr[i] * rinv * nsc[i];
    tf[(size_t)t * HD + i] = v;
    tb[(size_t)t * HD + i] = __float2bfloat16(v);
  }
}

// ---------------- Router ----------------
__global__ __launch_bounds__(256)
void router_k(const float* __restrict__ tf, const float* __restrict__ gw,
              const float* __restrict__ gb, float* __restrict__ wpair,
              int* __restrict__ cnt, int* __restrict__ tok_list, int* __restrict__ pair_list)
{
  int t = blockIdx.x;
  int tid = threadIdx.x;
  int e = tid >> 4, l16 = tid & 15;
  const float* tr = tf + (size_t)t * HD;
  float s = 0.f;
  for (int i = l16; i < HD; i += 16) s += tr[i] * gw[e * HD + i];
#pragma unroll
  for (int o = 1; o < 16; o <<= 1) s += __shfl_xor(s, o);
  __shared__ float logits[NEXP];
  if (l16 == 0) logits[e] = s + gb[e];
  __syncthreads();
  if (tid == 0) {
    float v[NEXP];
#pragma unroll
    for (int i = 0; i < NEXP; ++i) v[i] = logits[i];
    int idx[TOPK]; float val[TOPK];
#pragma unroll
    for (int k = 0; k < TOPK; ++k) {
      int bi = 0; float bv = -1e30f;
      for (int i = 0; i < NEXP; ++i) if (v[i] > bv) { bv = v[i]; bi = i; }
      idx[k] = bi; val[k] = bv; v[bi] = -1e30f;
    }
    float mx = val[0], sum = 0.f, w[TOPK];
#pragma unroll
    for (int k = 0; k < TOPK; ++k) { w[k] = __expf(val[k] - mx); sum += w[k]; }
#pragma unroll
    for (int k = 0; k < TOPK; ++k) {
      float wk = w[k] / sum;
      int ee = idx[k];
      int slot = atomicAdd(&cnt[ee], 1);
      tok_list[ee * NTOK + slot]  = t;
      pair_list[ee * NTOK + slot] = t * TOPK + k;
      wpair[t * TOPK + k] = wk;
    }
  }
}

// ---------------- Grouped GEMM: double-buffered 2-phase, syncthreads-only sync ----------------
template<int STAGE>
__global__ __launch_bounds__(256)
void moe_gemm(const __hip_bfloat16* __restrict__ Asrc,
              const int* __restrict__ Bblk, const int* __restrict__ Bscl,
              const float* __restrict__ Bbias,
              const int* __restrict__ cnt,
              const int* __restrict__ tok_list, const int* __restrict__ pair_list,
              __hip_bfloat16* __restrict__ h_out, float* __restrict__ o_out)
{
  constexpr int NDIM = (STAGE == 1) ? N1 : HD;
  const int e  = blockIdx.z;
  const int ne = cnt[e];
  const int m0 = blockIdx.y * 128;
  if (m0 >= ne) return;
  const int n0 = blockIdx.x * 128;
  const int tid = threadIdx.x;
  const int wave = tid >> 6, lane = tid & 63;

  __shared__ __align__(16) char Abuf[2][16384];  // [128 rows][128 B] bf16, XOR-swizzled
  __shared__ __align__(16) char Bbuf[2][16384];

  const int* glist = (STAGE == 1 ? tok_list : pair_list) + e * NTOK;
  const int* plist = pair_list + e * NTOK;

  // --- A staging bases (4 issues of 256 lanes x 16B each) ---
  const char* agbase[4];
  int aldsoff[4];
#pragma unroll
  for (int i = 0; i < 4; ++i) {
    int o   = i * 4096 + tid * 16;
    int row = o >> 7;
    int scb = (o & 127) ^ ((row & 7) << 4);   // inverse-swizzled source chunk
    int slot = m0 + row; if (slot > ne - 1) slot = ne - 1;
    int gidx = glist[slot];
    agbase[i]  = (const char*)Asrc + (size_t)gidx * (HD * 2) + scb;
    aldsoff[i] = i * 4096 + wave * 1024;      // wave-uniform base; HW adds lane*16
  }

  // --- B staging: thread -> (row, group-half); clamped unconditional loads ---
  const int brow = tid >> 1, bgrp = tid & 1;
  int nidx = n0 + brow; if (nidx >= NDIM) nidx = NDIM - 1;
  const size_t brbase = (size_t)(e * NDIM + nidx) * NGRP;
  const int* bptr = Bblk + brbase * 16;
  int bdoff[4];
#pragma unroll
  for (int c = 0; c < 4; ++c) {
    int chunk = (bgrp * 4 + c) ^ (brow & 7);
    bdoff[c] = brow * 128 + chunk * 16;
  }

  // --- MFMA fragment LDS offsets (k-independent) ---
  const int l15 = lane & 15, l4 = lane >> 4;
  const int wm = (wave >> 1) * 64, wn = (wave & 1) * 64;
  int aoff[4][2], boff[4][2];
#pragma unroll
  for (int f = 0; f < 4; ++f) {
    int ra = wm + f * 16 + l15;
    int rb = wn + f * 16 + l15;
#pragma unroll
    for (int kk = 0; kk < 2; ++kk) {
      aoff[f][kk] = ra * 128 + ((kk * 64 + l4 * 16) ^ ((ra & 7) << 4));
      boff[f][kk] = rb * 128 + ((kk * 64 + l4 * 16) ^ ((rb & 7) << 4));
    }
  }

  f32x4 zero = {0.f, 0.f, 0.f, 0.f};
  f32x4 acc[4][4];
#pragma unroll
  for (int a = 0; a < 4; ++a)
#pragma unroll
    for (int b = 0; b < 4; ++b) acc[a][b] = zero;

  // --- prologue: stage tile 0 into buffer 0 ---
  {
#pragma unroll
    for (int i = 0; i < 4; ++i) async16(Abuf[0] + aldsoff[i], agbase[i]);
    const i32x4* bp = (const i32x4*)(bptr + bgrp * 16);
    i32x4 q0 = bp[0], q1 = bp[1], q2 = bp[2], q3 = bp[3];
    int sc = Bscl[brbase + bgrp];
    dq_store(q0, q1, q2, q3, sc,
             Bbuf[0] + bdoff[0], Bbuf[0] + bdoff[1], Bbuf[0] + bdoff[2], Bbuf[0] + bdoff[3]);
  }
  __syncthreads();

  for (int t = 0; t < NKT; ++t) {
    const int cur = t & 1, nxt = cur ^ 1;
    const bool more = (t + 1 < NKT);
    i32x4 p0, p1, p2, p3; int psc;
    if (more) {
      // issue next tile's loads now; latency hides under the MFMA phase
#pragma unroll
      for (int i = 0; i < 4; ++i) async16(Abuf[nxt] + aldsoff[i], agbase[i] + (t + 1) * 128);
      const int gn = (t + 1) * 2 + bgrp;
      const i32x4* bp = (const i32x4*)(bptr + gn * 16);
      p0 = bp[0]; p1 = bp[1]; p2 = bp[2]; p3 = bp[3];
      psc = Bscl[brbase + gn];
    }

    // MFMA on current buffer
    const char* Ab = Abuf[cur];
    const char* Bb = Bbuf[cur];
    __builtin_amdgcn_s_setprio(1);
#pragma unroll
    for (int kk = 0; kk < 2; ++kk) {
      short8 af[4], bf[4];
#pragma unroll
      for (int f = 0; f < 4; ++f) {
        af[f] = *(const short8*)(Ab + aoff[f][kk]);
        bf[f] = *(const short8*)(Bb + boff[f][kk]);
      }
#pragma unroll
      for (int ma = 0; ma < 4; ++ma)
#pragma unroll
        for (int nb = 0; nb < 4; ++nb)
          acc[ma][nb] = __builtin_amdgcn_mfma_f32_16x16x32_bf16(af[ma], bf[nb], acc[ma][nb], 0, 0, 0);
    }
    __builtin_amdgcn_s_setprio(0);

    if (more) {
      dq_store(p0, p1, p2, p3, psc,
               Bbuf[nxt] + bdoff[0], Bbuf[nxt] + bdoff[1],
               Bbuf[nxt] + bdoff[2], Bbuf[nxt] + bdoff[3]);
    }
    __syncthreads();   // full drain: my asyncA + ds_writes done; safe buffer swap
  }

  // --- epilogue ---
  if (STAGE == 1) {
#pragma unroll
    for (int ma = 0; ma < 4; ++ma) {
#pragma unroll
      for (int nb = 0; nb < 4; ++nb) {
        int ncol = n0 + wn + nb * 16 + l15;
        float bias = Bbias[e * NDIM + ncol];
#pragma unroll
        for (int j = 0; j < 4; ++j) {
          float u  = acc[ma][nb][j] + bias;
          float up = __shfl_xor(u, 1);
          int slot = m0 + wm + ma * 16 + l4 * 4 + j;
          if (!(lane & 1) && slot < ne) {
            float g  = fminf(u, 7.f);
            float lv = fminf(fmaxf(up, -7.f), 7.f);
            float hv = g / (1.f + __expf(-1.702f * g)) * (lv + 1.f);
            h_out[(size_t)plist[slot] * ID + (ncol >> 1)] = __float2bfloat16(hv);
          }
        }
      }
    }
  } else {
#pragma unroll
    for (int ma = 0; ma < 4; ++ma) {
#pragma unroll
      for (int nb = 0; nb < 4; ++nb) {
        int ncol = n0 + wn + nb * 16 + l15;
        if (ncol < NDIM) {
          float bias = Bbias[e * NDIM + ncol];
#pragma unroll
          for (int j = 0; j < 4; ++j) {
            int slot = m0 + wm + ma * 16 + l4 * 4 + j;
            if (slot < ne)
              o_out[(size_t)plist[slot] * HD + ncol] = acc[ma][nb][j] + bias;
          }
        }
      }
    }
  }
}

// ---------------- Final combine ----------------
__global__ __launch_bounds__(256)
void final_k(const float* __restrict__ x, const float* __restrict__ obuf,
             const float* __restrict__ wpair, float* __restrict__ out)
{
  int t = blockIdx.x;
  float w0 = wpair[t * 4 + 0], w1 = wpair[t * 4 + 1];
  float w2 = wpair[t * 4 + 2], w3 = wpair[t * 4 + 3];
  const float* o0 = obuf + (size_t)(t * 4) * HD;
  for (int i = threadIdx.x; i < HD; i += 256) {
    float r = x[(size_t)t * HD + i]
            + w0 * o0[i] + w1 * o0[HD + i] + w2 * o0[2 * HD + i] + w3 * o0[3 * HD + i];
    out[(size_t)t * HD + i] = r;
  }
}

extern "C" void kernel_launch(void* const* d_in, const int* in_sizes, int n_in,
                              void* d_out, int out_size, void* d_ws, size_t ws_size,
                              hipStream_t stream)
{
  const float* x    = (const float*)d_in[0];
  const float* nsc  = (const float*)d_in[1];
  const float* gw   = (const float*)d_in[2];
  const float* gb   = (const float*)d_in[3];
  const int*   b1   = (const int*)d_in[4];
  const int*   s1   = (const int*)d_in[5];
  const float* bia1 = (const float*)d_in[6];
  const int*   b2   = (const int*)d_in[7];
  const int*   s2   = (const int*)d_in[8];
  const float* bia2 = (const float*)d_in[9];
  float* out = (float*)d_out;

  char* ws = (char*)d_ws;
  size_t off = 0;
  auto alloc = [&](size_t bytes) {
    char* p = ws + off;
    off = (off + bytes + 255) & ~(size_t)255;
    return p;
  };
  float*           tf    = (float*)alloc((size_t)NTOK * HD * 4);
  __hip_bfloat16*  tb    = (__hip_bfloat16*)alloc((size_t)NTOK * HD * 2);
  __hip_bfloat16*  hbuf  = (__hip_bfloat16*)alloc((size_t)NTOK * TOPK * ID * 2);
  float*           obuf  = (float*)alloc((size_t)NTOK * TOPK * HD * 4);
  float*           wpair = (float*)alloc(NTOK * TOPK * 4);
  int*             cnt   = (int*)alloc(64);
  int*             tokl  = (int*)alloc(NEXP * NTOK * 4);
  int*             pairl = (int*)alloc(NEXP * NTOK * 4);

  hipMemsetAsync(cnt, 0, NEXP * sizeof(int), stream);
  rmsnorm_k<<<NTOK, 256, 0, stream>>>(x, nsc, tf, tb);
  router_k<<<NTOK, 256, 0, stream>>>(tf, gw, gb, wpair, cnt, tokl, pairl);
  moe_gemm<1><<<dim3(N1 / 128, 4, NEXP), 256, 0, stream>>>(tb, b1, s1, bia1, cnt, tokl, pairl, hbuf, nullptr);
  moe_gemm<2><<<dim3((HD + 127) / 128, 4, NEXP), 256, 0, stream>>>(hbuf, b2, s2, bia2, cnt, tokl, pairl, nullptr, obuf);
  final_k<<<NTOK, 256, 0, stream>>>(x, obuf, wpair, out);
}

// Round 4
// 517.644 us; speedup vs baseline: 1.4898x; 1.0836x over previous
//
#include <hip/hip_runtime.h>
#include <hip/hip_bf16.h>

typedef __attribute__((ext_vector_type(8))) short short8;
typedef __attribute__((ext_vector_type(4))) float f32x4;
typedef __attribute__((ext_vector_type(4))) int i32x4;
typedef __attribute__((ext_vector_type(4))) unsigned u32x4;

#define NTOK 512
#define NEXP 16
#define TOPK 4
#define HD   2880
#define ID   2880
#define N1   5760   // 2*I
#define NGRP 90     // 32-value groups per row
#define NKT  45     // HD/64 K-steps

__device__ __forceinline__ unsigned perm(unsigned hi, unsigned lo, unsigned sel) {
  return __builtin_amdgcn_perm(hi, lo, sel);
}

// ---------------- perm-LUT MXFP4 dequant (bit-exact bf16, scale folded) ----------------
__device__ __forceinline__ u32x4 dq_word4(unsigned p, unsigned hbl, unsigned hbh,
                                          unsigned lbl, unsigned lbh) {
  unsigned ph = p >> 4;
  unsigned il = p  & 0x07070707u, sl = p  & 0x08080808u;
  unsigned ih = ph & 0x07070707u, sh = ph & 0x08080808u;
  unsigned hbL = perm(hbh, hbl, il) | (sl << 4);
  unsigned lbL = perm(lbh, lbl, il);
  unsigned hbH = perm(hbh, hbl, ih) | (sh << 4);
  unsigned lbH = perm(lbh, lbl, ih);
  unsigned mL01 = perm(hbL, lbL, 0x05010400u);
  unsigned mL23 = perm(hbL, lbL, 0x07030602u);
  unsigned mH01 = perm(hbH, lbH, 0x05010400u);
  unsigned mH23 = perm(hbH, lbH, 0x07030602u);
  u32x4 w;
  w.x = perm(mH01, mL01, 0x05040100u);
  w.y = perm(mH01, mL01, 0x07060302u);
  w.z = perm(mH23, mL23, 0x05040100u);
  w.w = perm(mH23, mL23, 0x07060302u);
  return w;
}

__device__ __forceinline__ void dq_store(i32x4 q0, i32x4 q1, i32x4 q2, i32x4 q3, int sc,
                                         char* d0, char* d1, char* d2, char* d3) {
  unsigned m7 = (unsigned)((127 - sc) << 7);          // sc in [118,127]
  unsigned mm = m7 | (m7 << 16);
  unsigned e10 = (0x3F00u - m7) << 16;                // entry0 stays exact 0
  unsigned e32 = 0x3FC03F80u - mm;
  unsigned e54 = 0x40404000u - mm;
  unsigned e76 = 0x40C04080u - mm;
  unsigned hbl = perm(e32, e10, 0x07050301u);
  unsigned hbh = perm(e76, e54, 0x07050301u);
  unsigned lbl = perm(e32, e10, 0x06040200u);
  unsigned lbh = perm(e76, e54, 0x06040200u);
  unsigned pk;
  pk = (unsigned)q0.x | ((unsigned)q0.y << 8) | ((unsigned)q0.z << 16) | ((unsigned)q0.w << 24);
  *(u32x4*)d0 = dq_word4(pk, hbl, hbh, lbl, lbh);
  pk = (unsigned)q1.x | ((unsigned)q1.y << 8) | ((unsigned)q1.z << 16) | ((unsigned)q1.w << 24);
  *(u32x4*)d1 = dq_word4(pk, hbl, hbh, lbl, lbh);
  pk = (unsigned)q2.x | ((unsigned)q2.y << 8) | ((unsigned)q2.z << 16) | ((unsigned)q2.w << 24);
  *(u32x4*)d2 = dq_word4(pk, hbl, hbh, lbl, lbh);
  pk = (unsigned)q3.x | ((unsigned)q3.y << 8) | ((unsigned)q3.z << 16) | ((unsigned)q3.w << 24);
  *(u32x4*)d3 = dq_word4(pk, hbl, hbh, lbl, lbh);
}

// ---------------- RMSNorm ----------------
__global__ __launch_bounds__(256)
void rmsnorm_k(const float* __restrict__ x, const float* __restrict__ nsc,
               float* __restrict__ tf, __hip_bfloat16* __restrict__ tb)
{
  int t = blockIdx.x;
  const float* xr = x + (size_t)t * HD;
  float s = 0.f;
  for (int i = threadIdx.x; i < HD; i += 256) { float v = xr[i]; s += v * v; }
#pragma unroll
  for (int o = 32; o > 0; o >>= 1) s += __shfl_down(s, o);
  __shared__ float red[4];
  if ((threadIdx.x & 63) == 0) red[threadIdx.x >> 6] = s;
  __syncthreads();
  float tot = red[0] + red[1] + red[2] + red[3];
  float rinv = rsqrtf(tot / (float)HD + 1e-5f);
  for (int i = threadIdx.x; i < HD; i += 256) {
    float v = xr[i] * rinv * nsc[i];
    tf[(size_t)t * HD + i] = v;
    tb[(size_t)t * HD + i] = __float2bfloat16(v);
  }
}

// ---------------- Router ----------------
__global__ __launch_bounds__(256)
void router_k(const float* __restrict__ tf, const float* __restrict__ gw,
              const float* __restrict__ gb, float* __restrict__ wpair,
              int* __restrict__ cnt, int* __restrict__ tok_list, int* __restrict__ pair_list)
{
  int t = blockIdx.x;
  int tid = threadIdx.x;
  int e = tid >> 4, l16 = tid & 15;
  const float* tr = tf + (size_t)t * HD;
  float s = 0.f;
  for (int i = l16; i < HD; i += 16) s += tr[i] * gw[e * HD + i];
#pragma unroll
  for (int o = 1; o < 16; o <<= 1) s += __shfl_xor(s, o);
  __shared__ float logits[NEXP];
  if (l16 == 0) logits[e] = s + gb[e];
  __syncthreads();
  if (tid == 0) {
    float v[NEXP];
#pragma unroll
    for (int i = 0; i < NEXP; ++i) v[i] = logits[i];
    int idx[TOPK]; float val[TOPK];
#pragma unroll
    for (int k = 0; k < TOPK; ++k) {
      int bi = 0; float bv = -1e30f;
      for (int i = 0; i < NEXP; ++i) if (v[i] > bv) { bv = v[i]; bi = i; }
      idx[k] = bi; val[k] = bv; v[bi] = -1e30f;
    }
    float mx = val[0], sum = 0.f, w[TOPK];
#pragma unroll
    for (int k = 0; k < TOPK; ++k) { w[k] = __expf(val[k] - mx); sum += w[k]; }
#pragma unroll
    for (int k = 0; k < TOPK; ++k) {
      float wk = w[k] / sum;
      int ee = idx[k];
      int slot = atomicAdd(&cnt[ee], 1);
      tok_list[ee * NTOK + slot]  = t;
      pair_list[ee * NTOK + slot] = t * TOPK + k;
      wpair[t * TOPK + k] = wk;
    }
  }
}

// ---------------- Grouped GEMM: depth-2 reg-staged pipeline, raw barriers,
// ---------------- all VMEM waits compiler-managed (no hand-counted vmcnt) ----
template<int STAGE>
__global__ __launch_bounds__(256)
void moe_gemm(const __hip_bfloat16* __restrict__ Asrc,
              const int* __restrict__ Bblk, const int* __restrict__ Bscl,
              const float* __restrict__ Bbias,
              const int* __restrict__ cnt,
              const int* __restrict__ tok_list, const int* __restrict__ pair_list,
              __hip_bfloat16* __restrict__ h_out, float* __restrict__ o_out)
{
  constexpr int NDIM = (STAGE == 1) ? N1 : HD;
  const int e  = blockIdx.z;
  const int ne = cnt[e];
  const int m0 = blockIdx.y * 128;
  if (m0 >= ne) return;
  const int n0 = blockIdx.x * 128;
  const int tid = threadIdx.x;
  const int wave = tid >> 6, lane = tid & 63;

  __shared__ __align__(16) char Abuf[2][16384];  // [128 rows][128 B] bf16, XOR-swizzled
  __shared__ __align__(16) char Bbuf[2][16384];

  const int* glist = (STAGE == 1 ? tok_list : pair_list) + e * NTOK;
  const int* plist = pair_list + e * NTOK;

  // --- A reg-staging: thread -> (row, 64B-half). Swizzle applied on WRITE side. ---
  const int arow = tid >> 1, akc = tid & 1;
  int aslot = m0 + arow; if (aslot > ne - 1) aslot = ne - 1;
  const char* agp = (const char*)Asrc + (size_t)glist[aslot] * (HD * 2) + akc * 64;
  int awoff[4];
#pragma unroll
  for (int c = 0; c < 4; ++c)
    awoff[c] = arow * 128 + ((akc * 64 + c * 16) ^ ((arow & 7) << 4));

  // --- B staging: thread -> (row, group-half); clamped unconditional loads ---
  const int brow = tid >> 1, bgrp = tid & 1;
  int nidx = n0 + brow; if (nidx >= NDIM) nidx = NDIM - 1;
  const size_t brbase = (size_t)(e * NDIM + nidx) * NGRP;
  const int* bptr = Bblk + brbase * 16;
  int bdoff[4];
#pragma unroll
  for (int c = 0; c < 4; ++c) {
    int chunk = (bgrp * 4 + c) ^ (brow & 7);
    bdoff[c] = brow * 128 + chunk * 16;
  }

  // --- MFMA fragment LDS read offsets (k-independent) ---
  const int l15 = lane & 15, l4 = lane >> 4;
  const int wm = (wave >> 1) * 64, wn = (wave & 1) * 64;
  int aoff[4][2], boff[4][2];
#pragma unroll
  for (int f = 0; f < 4; ++f) {
    int ra = wm + f * 16 + l15;
    int rb = wn + f * 16 + l15;
#pragma unroll
    for (int kk = 0; kk < 2; ++kk) {
      aoff[f][kk] = ra * 128 + ((kk * 64 + l4 * 16) ^ ((ra & 7) << 4));
      boff[f][kk] = rb * 128 + ((kk * 64 + l4 * 16) ^ ((rb & 7) << 4));
    }
  }

  f32x4 zero = {0.f, 0.f, 0.f, 0.f};
  f32x4 acc[4][4];
#pragma unroll
  for (int a = 0; a < 4; ++a)
#pragma unroll
    for (int b = 0; b < 4; ++b) acc[a][b] = zero;

  // --- staged registers (single set; write(t+1) reads them before issue(t+2) overwrites) ---
  i32x4 a0, a1, a2, a3;        // A: 64 bytes
  i32x4 q0, q1, q2, q3; int sc;  // B: 64 bytes nibbles (int32-widened) + scale

  // --- prologue: load(0); write(0)->buf0; load(1) ---
  {
    const i32x4* ap = (const i32x4*)agp;
    a0 = ap[0]; a1 = ap[1]; a2 = ap[2]; a3 = ap[3];
    const i32x4* bp = (const i32x4*)(bptr + bgrp * 16);
    q0 = bp[0]; q1 = bp[1]; q2 = bp[2]; q3 = bp[3];
    sc = Bscl[brbase + bgrp];
  }
  *(i32x4*)(Abuf[0] + awoff[0]) = a0;
  *(i32x4*)(Abuf[0] + awoff[1]) = a1;
  *(i32x4*)(Abuf[0] + awoff[2]) = a2;
  *(i32x4*)(Abuf[0] + awoff[3]) = a3;
  dq_store(q0, q1, q2, q3, sc,
           Bbuf[0] + bdoff[0], Bbuf[0] + bdoff[1], Bbuf[0] + bdoff[2], Bbuf[0] + bdoff[3]);
  {
    const i32x4* ap = (const i32x4*)(agp + 128);
    a0 = ap[0]; a1 = ap[1]; a2 = ap[2]; a3 = ap[3];
    const int gn = 2 + bgrp;
    const i32x4* bp = (const i32x4*)(bptr + gn * 16);
    q0 = bp[0]; q1 = bp[1]; q2 = bp[2]; q3 = bp[3];
    sc = Bscl[brbase + gn];
  }
  asm volatile("s_waitcnt lgkmcnt(0)" ::: "memory");
  __builtin_amdgcn_sched_barrier(0);
  __builtin_amdgcn_s_barrier();
  __builtin_amdgcn_sched_barrier(0);

  for (int t = 0; t < NKT; ++t) {
    const int cur = t & 1, nxt = cur ^ 1;

    // phase W: write staged tile t+1 into buf[nxt] (regs loaded a full iteration ago)
    if (t + 1 < NKT) {
      *(i32x4*)(Abuf[nxt] + awoff[0]) = a0;
      *(i32x4*)(Abuf[nxt] + awoff[1]) = a1;
      *(i32x4*)(Abuf[nxt] + awoff[2]) = a2;
      *(i32x4*)(Abuf[nxt] + awoff[3]) = a3;
      dq_store(q0, q1, q2, q3, sc,
               Bbuf[nxt] + bdoff[0], Bbuf[nxt] + bdoff[1],
               Bbuf[nxt] + bdoff[2], Bbuf[nxt] + bdoff[3]);
    }
    // phase I: issue loads for tile t+2 (stay in flight across both raw barriers)
    if (t + 2 < NKT) {
      const i32x4* ap = (const i32x4*)(agp + (t + 2) * 128);
      a0 = ap[0]; a1 = ap[1]; a2 = ap[2]; a3 = ap[3];
      const int gn = (t + 2) * 2 + bgrp;
      const i32x4* bp = (const i32x4*)(bptr + gn * 16);
      q0 = bp[0]; q1 = bp[1]; q2 = bp[2]; q3 = bp[3];
      sc = Bscl[brbase + gn];
    }
    asm volatile("s_waitcnt lgkmcnt(0)" ::: "memory");  // ds_writes visible; no vmem drain
    __builtin_amdgcn_sched_barrier(0);
    __builtin_amdgcn_s_barrier();
    __builtin_amdgcn_sched_barrier(0);

    // phase C: MFMA on buf[cur]
    __builtin_amdgcn_s_setprio(1);
#pragma unroll
    for (int kk = 0; kk < 2; ++kk) {
      short8 af[4], bf[4];
#pragma unroll
      for (int f = 0; f < 4; ++f) {
        af[f] = *(const short8*)(Abuf[cur] + aoff[f][kk]);
        bf[f] = *(const short8*)(Bbuf[cur] + boff[f][kk]);
      }
#pragma unroll
      for (int ma = 0; ma < 4; ++ma)
#pragma unroll
        for (int nb = 0; nb < 4; ++nb)
          acc[ma][nb] = __builtin_amdgcn_mfma_f32_16x16x32_bf16(af[ma], bf[nb], acc[ma][nb], 0, 0, 0);
    }
    __builtin_amdgcn_s_setprio(0);
    __builtin_amdgcn_sched_barrier(0);
    __builtin_amdgcn_s_barrier();
    __builtin_amdgcn_sched_barrier(0);
  }

  // --- epilogue ---
  if (STAGE == 1) {
#pragma unroll
    for (int ma = 0; ma < 4; ++ma) {
#pragma unroll
      for (int nb = 0; nb < 4; ++nb) {
        int ncol = n0 + wn + nb * 16 + l15;
        float bias = Bbias[e * NDIM + ncol];
#pragma unroll
        for (int j = 0; j < 4; ++j) {
          float u  = acc[ma][nb][j] + bias;
          float up = __shfl_xor(u, 1);
          int slot = m0 + wm + ma * 16 + l4 * 4 + j;
          if (!(lane & 1) && slot < ne) {
            float g  = fminf(u, 7.f);
            float lv = fminf(fmaxf(up, -7.f), 7.f);
            float hv = g / (1.f + __expf(-1.702f * g)) * (lv + 1.f);
            h_out[(size_t)plist[slot] * ID + (ncol >> 1)] = __float2bfloat16(hv);
          }
        }
      }
    }
  } else {
#pragma unroll
    for (int ma = 0; ma < 4; ++ma) {
#pragma unroll
      for (int nb = 0; nb < 4; ++nb) {
        int ncol = n0 + wn + nb * 16 + l15;
        if (ncol < NDIM) {
          float bias = Bbias[e * NDIM + ncol];
#pragma unroll
          for (int j = 0; j < 4; ++j) {
            int slot = m0 + wm + ma * 16 + l4 * 4 + j;
            if (slot < ne)
              o_out[(size_t)plist[slot] * HD + ncol] = acc[ma][nb][j] + bias;
          }
        }
      }
    }
  }
}

// ---------------- Final combine ----------------
__global__ __launch_bounds__(256)
void final_k(const float* __restrict__ x, const float* __restrict__ obuf,
             const float* __restrict__ wpair, float* __restrict__ out)
{
  int t = blockIdx.x;
  float w0 = wpair[t * 4 + 0], w1 = wpair[t * 4 + 1];
  float w2 = wpair[t * 4 + 2], w3 = wpair[t * 4 + 3];
  const float* o0 = obuf + (size_t)(t * 4) * HD;
  for (int i = threadIdx.x; i < HD; i += 256) {
    float r = x[(size_t)t * HD + i]
            + w0 * o0[i] + w1 * o0[HD + i] + w2 * o0[2 * HD + i] + w3 * o0[3 * HD + i];
    out[(size_t)t * HD + i] = r;
  }
}

extern "C" void kernel_launch(void* const* d_in, const int* in_sizes, int n_in,
                              void* d_out, int out_size, void* d_ws, size_t ws_size,
                              hipStream_t stream)
{
  const float* x    = (const float*)d_in[0];
  const float* nsc  = (const float*)d_in[1];
  const float* gw   = (const float*)d_in[2];
  const float* gb   = (const float*)d_in[3];
  const int*   b1   = (const int*)d_in[4];
  const int*   s1   = (const int*)d_in[5];
  const float* bia1 = (const float*)d_in[6];
  const int*   b2   = (const int*)d_in[7];
  const int*   s2   = (const int*)d_in[8];
  const float* bia2 = (const float*)d_in[9];
  float* out = (float*)d_out;

  char* ws = (char*)d_ws;
  size_t off = 0;
  auto alloc = [&](size_t bytes) {
    char* p = ws + off;
    off = (off + bytes + 255) & ~(size_t)255;
    return p;
  };
  float*           tf    = (float*)alloc((size_t)NTOK * HD * 4);
  __hip_bfloat16*  tb    = (__hip_bfloat16*)alloc((size_t)NTOK * HD * 2);
  __hip_bfloat16*  hbuf  = (__hip_bfloat16*)alloc((size_t)NTOK * TOPK * ID * 2);
  float*           obuf  = (float*)alloc((size_t)NTOK * TOPK * HD * 4);
  float*           wpair = (float*)alloc(NTOK * TOPK * 4);
  int*             cnt   = (int*)alloc(64);
  int*             tokl  = (int*)alloc(NEXP * NTOK * 4);
  int*             pairl = (int*)alloc(NEXP * NTOK * 4);

  hipMemsetAsync(cnt, 0, NEXP * sizeof(int), stream);
  rmsnorm_k<<<NTOK, 256, 0, stream>>>(x, nsc, tf, tb);
  router_k<<<NTOK, 256, 0, stream>>>(tf, gw, gb, wpair, cnt, tokl, pairl);
  moe_gemm<1><<<dim3(N1 / 128, 4, NEXP), 256, 0, stream>>>(tb, b1, s1, bia1, cnt, tokl, pairl, hbuf, nullptr);
  moe_gemm<2><<<dim3((HD + 127) / 128, 4, NEXP), 256, 0, stream>>>(hbuf, b2, s2, bia2, cnt, tokl, pairl, nullptr, obuf);
  final_k<<<NTOK, 256, 0, stream>>>(x, obuf, wpair, out);
}